// Round 1
// baseline (313.794 us; speedup 1.0000x reference)
//
#include <hip/hip_runtime.h>
#include <math.h>

#define B_   4
#define EC_  32
#define E_   48
#define S_   2048
#define F_   128
#define PK_  (6*F_ + 16)   // per-(b,e) park floats: g1',b1,g2',b2,g3',b3, geo[16]
#define TS_  64            // samples per tile in main kernel

// per-(b,e) precomputed parameters (written by precompute_kernel each launch)
__device__ float g_park[B_ * E_ * PK_];

// ---------------------------------------------------------------------------
// Kernel 1: per-(b,e) CBN gamma'/beta GEMVs + geometry (const, center, 1/std, rot)
// grid = 192 blocks, 128 threads
// ---------------------------------------------------------------------------
__global__ __launch_bounds__(128) void precompute_kernel(
    const float* __restrict__ packed,
    const float* __restrict__ bw1, const float* __restrict__ bb1,
    const float* __restrict__ gw1, const float* __restrict__ gb1,
    const float* __restrict__ bw2, const float* __restrict__ bb2,
    const float* __restrict__ gw2, const float* __restrict__ gb2,
    const float* __restrict__ bw3, const float* __restrict__ bb3,
    const float* __restrict__ gw3, const float* __restrict__ gb3)
{
    const int be = blockIdx.x;         // 0..191
    const int b  = be / E_;
    const int e  = be - b * E_;
    const int ec = (e < EC_) ? e : (e - EC_);   // _tile: e>=32 -> source e-32 (in [0,16))
    const float* pv = packed + (size_t)(b * EC_ + ec) * 138;

    __shared__ float emb[F_];
    const int t = threadIdx.x;
    emb[t] = pv[10 + t];
    __syncthreads();

    float s_b1 = 0.f, s_g1 = 0.f, s_b2 = 0.f, s_g2 = 0.f, s_b3 = 0.f, s_g3 = 0.f;
    for (int k = 0; k < F_; ++k) {
        const float ek = emb[k];
        s_b1 = fmaf(ek, bw1[k * F_ + t], s_b1);
        s_g1 = fmaf(ek, gw1[k * F_ + t], s_g1);
        s_b2 = fmaf(ek, bw2[k * F_ + t], s_b2);
        s_g2 = fmaf(ek, gw2[k * F_ + t], s_g2);
        s_b3 = fmaf(ek, bw3[k * F_ + t], s_b3);
        s_g3 = fmaf(ek, gw3[k * F_ + t], s_g3);
    }

    const float inv = 0.99999500003749984f;   // 1/sqrt(1 + 1e-5)
    float* p = g_park + (size_t)be * PK_;
    p[0 * F_ + t] = (s_g1 + gb1[t]) * inv;    // gamma1' (inv folded in)
    p[1 * F_ + t] =  s_b1 + bb1[t];           // beta1
    p[2 * F_ + t] = (s_g2 + gb2[t]) * inv;
    p[3 * F_ + t] =  s_b2 + bb2[t];
    p[4 * F_ + t] = (s_g3 + gb3[t]) * inv;
    p[5 * F_ + t] =  s_b3 + bb3[t];

    if (t == 0) {
        float* g = p + 6 * F_;
        const float c  = pv[0];
        const float cx = pv[1], cy = pv[2], cz = pv[3];
        const float sx = fmaxf(pv[4], 1e-4f);
        const float sy = fmaxf(pv[5], 1e-4f);
        const float sz = fmaxf(pv[6], 1e-4f);
        const float ar = pv[7], ap = pv[8], ay = pv[9];
        const float cr = cosf(ar), sr = sinf(ar);
        const float cp = cosf(ap), sp = sinf(ap);
        const float cyw = cosf(ay), syw = sinf(ay);
        g[0] = c;  g[1] = cx;  g[2] = cy;  g[3] = cz;
        g[4] = 1.f / sx;  g[5] = 1.f / sy;  g[6] = 1.f / sz;
        // rot row-major rot[i][j]; local_j = sum_i diff_i * rot[i][j]
        g[7]  = cyw * cp;                   g[8]  = cyw * sp * sr - syw * cr;   g[9]  = cyw * sp * cr + syw * sr;
        g[10] = syw * cp;                   g[11] = syw * sp * sr + cyw * cr;   g[12] = syw * sp * cr - cyw * sr;
        g[13] = -sp;                        g[14] = cp * sr;                    g[15] = cp * cr;
    }
}

// ---------------------------------------------------------------------------
// Kernel 2: fused geometry + MLP + reduction
// grid = 192 * (S/TS) = 6144 blocks, 256 threads = 64 samples x 4 feature-waves
// ---------------------------------------------------------------------------
__global__ __launch_bounds__(256) void ldif_main(
    const float* __restrict__ samples,
    const float* __restrict__ fc1w, const float* __restrict__ fc1b,
    const float* __restrict__ rw1,  const float* __restrict__ rb1,
    const float* __restrict__ rw2,  const float* __restrict__ rb2,
    const float* __restrict__ fc2w, const float* __restrict__ fc2b,
    float* __restrict__ out)
{
    const int tile = blockIdx.x & 31;      // S_/TS_ = 32 tiles
    const int be   = blockIdx.x >> 5;      // 0..191
    const int b    = be / E_;
    const int e    = be - b * E_;
    const bool zflip = (e >= EC_);
    const float* park = g_park + (size_t)be * PK_;
    const float* geo  = park + 6 * F_;

    __shared__ float lsw[TS_][4];          // ls0, ls1, ls2, weight
    __shared__ float act[TS_][133];        // stride 133: bank = (5s+k)%32, gcd(5,32)=1
    __shared__ float red[TS_][4];

    const int t = threadIdx.x;
    const int s = t & 63;                  // sample within tile
    const int w = t >> 6;                  // wave = feature group

    // ---- phase 0: geometry per sample (wave 0's lanes only) ----
    if (t < TS_) {
        const float* sp = samples + ((size_t)b * S_ + (size_t)tile * TS_ + t) * 3;
        float x = sp[0], y = sp[1], z = sp[2];
        if (zflip) z = -z;
        const float dx = x - geo[1], dy = y - geo[2], dz = z - geo[3];
        float l0 = dx * geo[7] + dy * geo[10] + dz * geo[13];
        float l1 = dx * geo[8] + dy * geo[11] + dz * geo[14];
        float l2 = dx * geo[9] + dy * geo[12] + dz * geo[15];
        l0 *= geo[4]; l1 *= geo[5]; l2 *= geo[6];
        const float wgt = __expf(-0.5f * (l0 * l0 + l1 * l1 + l2 * l2));
        lsw[t][0] = l0; lsw[t][1] = l1; lsw[t][2] = l2; lsw[t][3] = wgt;
    }
    __syncthreads();

    const int f0 = __builtin_amdgcn_readfirstlane(w * 32);   // wave-uniform feature base

    // ---- phase 1: fc1 + CBN1; init_h in regs; relu(h1) -> LDS ----
    const float ls0 = lsw[s][0], ls1 = lsw[s][1], ls2 = lsw[s][2];
    float inith[32];
    #pragma unroll
    for (int j = 0; j < 32; ++j) {
        const int f = f0 + j;
        float h0 = fmaf(ls0, fc1w[f],
                   fmaf(ls1, fc1w[F_ + f],
                   fmaf(ls2, fc1w[2 * F_ + f], fc1b[f])));
        const float h1 = fmaf(park[f], h0, park[F_ + f]);
        inith[j] = h1;
        act[s][f] = fmaxf(h1, 0.f);
    }
    __syncthreads();

    // ---- phase 2: GEMM1 (relu(h1) @ rfc1_w + rfc1_b) ----
    float acc[32];
    #pragma unroll
    for (int j = 0; j < 32; ++j) acc[j] = rb1[f0 + j];
    for (int k = 0; k < F_; ++k) {
        const float a = act[s][k];
        const float* wr = rw1 + k * F_ + f0;   // wave-uniform -> scalar loads
        #pragma unroll
        for (int j = 0; j < 32; ++j) acc[j] = fmaf(a, wr[j], acc[j]);
    }
    __syncthreads();   // everyone done reading act before overwrite

    // ---- CBN2 + relu -> LDS ----
    #pragma unroll
    for (int j = 0; j < 32; ++j) {
        const int f = f0 + j;
        const float h2 = fmaf(park[2 * F_ + f], acc[j], park[3 * F_ + f]);
        act[s][f] = fmaxf(h2, 0.f);
    }
    __syncthreads();

    // ---- phase 3: GEMM2 (relu(h2) @ rfc2_w + rfc2_b) ----
    #pragma unroll
    for (int j = 0; j < 32; ++j) acc[j] = rb2[f0 + j];
    for (int k = 0; k < F_; ++k) {
        const float a = act[s][k];
        const float* wr = rw2 + k * F_ + f0;
        #pragma unroll
        for (int j = 0; j < 32; ++j) acc[j] = fmaf(a, wr[j], acc[j]);
    }

    // ---- skip + CBN3 + fc2 partial dot ----
    float part = 0.f;
    #pragma unroll
    for (int j = 0; j < 32; ++j) {
        const int f = f0 + j;
        float hh = inith[j] + acc[j];
        hh = fmaf(park[4 * F_ + f], hh, park[5 * F_ + f]);
        part = fmaf(hh, fc2w[f], part);
    }
    red[s][w] = part;
    __syncthreads();

    // ---- phase 4: cross-wave reduce + output ----
    if (t < TS_) {
        const float val = red[t][0] + red[t][1] + red[t][2] + red[t][3] + fc2b[0];
        const float contrib = geo[0] * lsw[t][3] * (1.f + val);
        atomicAdd(&out[(size_t)b * S_ + (size_t)tile * TS_ + t], contrib);
    }
}

// ---------------------------------------------------------------------------
extern "C" void kernel_launch(void* const* d_in, const int* in_sizes, int n_in,
                              void* d_out, int out_size, void* d_ws, size_t ws_size,
                              hipStream_t stream) {
    (void)in_sizes; (void)n_in; (void)d_ws; (void)ws_size;

    const float* packed = (const float*)d_in[0];
    const float* samples = (const float*)d_in[1];
    const float* fc1w = (const float*)d_in[2];
    const float* fc1b = (const float*)d_in[3];
    const float* bw1  = (const float*)d_in[4];
    const float* bb1  = (const float*)d_in[5];
    const float* gw1  = (const float*)d_in[6];
    const float* gb1  = (const float*)d_in[7];
    const float* rw1  = (const float*)d_in[8];
    const float* rb1  = (const float*)d_in[9];
    const float* bw2  = (const float*)d_in[10];
    const float* bb2  = (const float*)d_in[11];
    const float* gw2  = (const float*)d_in[12];
    const float* gb2  = (const float*)d_in[13];
    const float* rw2  = (const float*)d_in[14];
    const float* rb2  = (const float*)d_in[15];
    const float* bw3  = (const float*)d_in[16];
    const float* bb3  = (const float*)d_in[17];
    const float* gw3  = (const float*)d_in[18];
    const float* gb3  = (const float*)d_in[19];
    const float* fc2w = (const float*)d_in[20];
    const float* fc2b = (const float*)d_in[21];
    float* out = (float*)d_out;

    hipMemsetAsync(out, 0, (size_t)out_size * sizeof(float), stream);

    precompute_kernel<<<B_ * E_, 128, 0, stream>>>(
        packed, bw1, bb1, gw1, gb1, bw2, bb2, gw2, gb2, bw3, bb3, gw3, gb3);

    ldif_main<<<B_ * E_ * (S_ / TS_), 256, 0, stream>>>(
        samples, fc1w, fc1b, rw1, rb1, rw2, rb2, fc2w, fc2b, out);
}

// Round 2
// 89.698 us; speedup vs baseline: 3.4983x; 3.4983x over previous
//
#include <hip/hip_runtime.h>
#include <math.h>

#define B_   4
#define EC_  32
#define E_   48
#define S_   2048
#define F_   128
#define PK_  (6*F_ + 16)   // park: g1',b1, g2',b2, g3w,[cbeta], geo[16]
#define TPW_ 4             // 64-sample tiles per WG
#define NST_ 8             // super-tiles per be (TPW_*64*NST_ == S_)

typedef __attribute__((ext_vector_type(8))) short short8;
typedef __attribute__((ext_vector_type(4))) float f32x4;

__device__ float g_park[B_ * E_ * PK_];
// bf16 weights in MFMA B-fragment order: [gemm 2][ntile 8][kstep 4][lane 64][elem 8]
__device__ __align__(16) short g_wfrag[2 * 8 * 4 * 64 * 8];

static __device__ __forceinline__ short f2bf(float x) {
    unsigned u = __float_as_uint(x);
    unsigned r = (u + 0x7FFFu + ((u >> 16) & 1u)) >> 16;   // RNE
    return (short)r;
}

// ---------------------------------------------------------------------------
// Kernel A: weights fp32 -> bf16 fragments.  B-frag (16x16x32): lane holds
// B[k][n] with n = nt*16 + (lane&15), k = ks*32 + (lane>>4)*8 + j.
// grid = 64 blocks (g*32 | nt*4 | ks) x 64 threads (lane)
// ---------------------------------------------------------------------------
__global__ __launch_bounds__(64) void prep_weights(
    const float* __restrict__ rw1, const float* __restrict__ rw2)
{
    const int bid = blockIdx.x;
    const int g   = bid >> 5;
    const int ntg = (bid >> 2) & 7;
    const int ks  = bid & 3;
    const int lane = threadIdx.x;
    const float* W = g ? rw2 : rw1;
    short8 v;
    #pragma unroll
    for (int j = 0; j < 8; ++j) {
        const int k = ks * 32 + (lane >> 4) * 8 + j;
        const int n = ntg * 16 + (lane & 15);
        v[j] = f2bf(W[k * F_ + n]);
    }
    *(short8*)&g_wfrag[(((g * 8 + ntg) * 4 + ks) * 64 + lane) * 8] = v;
}

// ---------------------------------------------------------------------------
// Kernel B: per-(b,e) CBN GEMVs + geometry. grid = 192 x 128 threads
// ---------------------------------------------------------------------------
__global__ __launch_bounds__(128) void precompute_kernel(
    const float* __restrict__ packed,
    const float* __restrict__ bw1, const float* __restrict__ bb1,
    const float* __restrict__ gw1, const float* __restrict__ gb1,
    const float* __restrict__ bw2, const float* __restrict__ bb2,
    const float* __restrict__ gw2, const float* __restrict__ gb2,
    const float* __restrict__ bw3, const float* __restrict__ bb3,
    const float* __restrict__ gw3, const float* __restrict__ gb3,
    const float* __restrict__ fc2w, const float* __restrict__ fc2b)
{
    const int be = blockIdx.x;
    const int b  = be / E_;
    const int e  = be - b * E_;
    const int ec = (e < EC_) ? e : (e - EC_);
    const float* pv = packed + (size_t)(b * EC_ + ec) * 138;

    __shared__ float emb[F_];
    __shared__ float sred[F_];
    const int t = threadIdx.x;
    emb[t] = pv[10 + t];
    __syncthreads();

    float s_b1 = 0.f, s_g1 = 0.f, s_b2 = 0.f, s_g2 = 0.f, s_b3 = 0.f, s_g3 = 0.f;
    for (int k = 0; k < F_; ++k) {
        const float ek = emb[k];
        s_b1 = fmaf(ek, bw1[k * F_ + t], s_b1);
        s_g1 = fmaf(ek, gw1[k * F_ + t], s_g1);
        s_b2 = fmaf(ek, bw2[k * F_ + t], s_b2);
        s_g2 = fmaf(ek, gw2[k * F_ + t], s_g2);
        s_b3 = fmaf(ek, bw3[k * F_ + t], s_b3);
        s_g3 = fmaf(ek, gw3[k * F_ + t], s_g3);
    }

    const float inv = 0.99999500003749984f;   // 1/sqrt(1+1e-5)
    float* p = g_park + (size_t)be * PK_;
    p[0 * F_ + t] = (s_g1 + gb1[t]) * inv;
    p[1 * F_ + t] =  s_b1 + bb1[t];
    p[2 * F_ + t] = (s_g2 + gb2[t]) * inv;
    p[3 * F_ + t] =  s_b2 + bb2[t];
    p[4 * F_ + t] = (s_g3 + gb3[t]) * inv * fc2w[t];      // g3w (fc2 folded)
    sred[t] = (s_b3 + bb3[t]) * fc2w[t];
    __syncthreads();

    if (t == 0) {
        float cb = fc2b[0];
        for (int i = 0; i < F_; ++i) cb += sred[i];
        p[5 * F_] = cb;                                    // cbeta

        float* g = p + 6 * F_;
        const float c  = pv[0];
        const float sx = fmaxf(pv[4], 1e-4f);
        const float sy = fmaxf(pv[5], 1e-4f);
        const float sz = fmaxf(pv[6], 1e-4f);
        const float ar = pv[7], ap = pv[8], ay = pv[9];
        const float cr = cosf(ar), sr = sinf(ar);
        const float cp = cosf(ap), sp = sinf(ap);
        const float cyw = cosf(ay), syw = sinf(ay);
        g[0] = c;  g[1] = pv[1];  g[2] = pv[2];  g[3] = pv[3];
        g[4] = 1.f / sx;  g[5] = 1.f / sy;  g[6] = 1.f / sz;
        g[7]  = cyw * cp;  g[8]  = cyw * sp * sr - syw * cr;  g[9]  = cyw * sp * cr + syw * sr;
        g[10] = syw * cp;  g[11] = syw * sp * sr + cyw * cr;  g[12] = syw * sp * cr - cyw * sr;
        g[13] = -sp;       g[14] = cp * sr;                   g[15] = cp * cr;
    }
}

// ---------------------------------------------------------------------------
// Kernel C: fused MFMA main.  grid = 192*NST_ WGs x 256 threads (4 waves).
// Wave w owns output cols [32w,32w+32) (2 ntiles), all 64 rows (4 mtiles).
// LDS act[64][128] bf16, XOR-swizzled:  byte = row*256 + (col2 ^ ((row&7)<<4))
// ---------------------------------------------------------------------------
__global__ __launch_bounds__(256, 2) void ldif_mfma(
    const float* __restrict__ samples,
    const float* __restrict__ fc1w, const float* __restrict__ fc1b,
    const float* __restrict__ rb1,  const float* __restrict__ rb2,
    float* __restrict__ out)
{
    const int bid = blockIdx.x;
    const int be  = bid / NST_;
    const int st  = bid - be * NST_;
    const int b   = be / E_;
    const int e   = be - b * E_;
    const bool zflip = (e >= EC_);
    const float* park = g_park + (size_t)be * PK_;
    const float* geo  = park + 6 * F_;

    __shared__ __align__(16) short act[64 * 128];   // 16 KB
    __shared__ __align__(16) float lsw[64][4];
    __shared__ float red[64][4];

    const int t  = threadIdx.x;
    const int w  = t >> 6;          // wave id = col block
    const int l  = t & 63;          // lane
    const int q  = l >> 4;          // quarter
    const int li = l & 15;

    // hoisted per-lane column constants (nt = 0,1 -> col = 32w+16nt+li)
    float fw0[2], fw1[2], fw2[2], fb[2], g1p[2], b1p[2], g2p[2], b2p[2];
    float r1b[2], r2b[2], g3w[2];
    #pragma unroll
    for (int nt = 0; nt < 2; ++nt) {
        const int col = w * 32 + nt * 16 + li;
        fw0[nt] = fc1w[col]; fw1[nt] = fc1w[F_ + col]; fw2[nt] = fc1w[2 * F_ + col];
        fb[nt]  = fc1b[col];
        g1p[nt] = park[col];          b1p[nt] = park[F_ + col];
        g2p[nt] = park[2 * F_ + col]; b2p[nt] = park[3 * F_ + col];
        g3w[nt] = park[4 * F_ + col];
        r1b[nt] = rb1[col];           r2b[nt] = rb2[col];
    }
    const float cbeta = park[5 * F_];

    // B fragments for both GEMMs, held in VGPRs for the whole WG lifetime
    short8 bfA[2][4], bfB[2][4];
    #pragma unroll
    for (int nt = 0; nt < 2; ++nt) {
        const int ntg = w * 2 + nt;
        #pragma unroll
        for (int ks = 0; ks < 4; ++ks) {
            bfA[nt][ks] = *(const short8*)&g_wfrag[(((0 * 8 + ntg) * 4 + ks) * 64 + l) * 8];
            bfB[nt][ks] = *(const short8*)&g_wfrag[(((1 * 8 + ntg) * 4 + ks) * 64 + l) * 8];
        }
    }

    for (int tile = 0; tile < TPW_; ++tile) {
        const int sbase = st * (TPW_ * 64) + tile * 64;

        // ---- phase 0: geometry ----
        if (t < 64) {
            const float* sp = samples + ((size_t)b * S_ + sbase + t) * 3;
            float x = sp[0], y = sp[1], z = sp[2];
            if (zflip) z = -z;
            const float dx = x - geo[1], dy = y - geo[2], dz = z - geo[3];
            const float l0 = (dx * geo[7] + dy * geo[10] + dz * geo[13]) * geo[4];
            const float l1 = (dx * geo[8] + dy * geo[11] + dz * geo[14]) * geo[5];
            const float l2 = (dx * geo[9] + dy * geo[12] + dz * geo[15]) * geo[6];
            const float wgt = __expf(-0.5f * (l0 * l0 + l1 * l1 + l2 * l2));
            lsw[t][0] = l0; lsw[t][1] = l1; lsw[t][2] = l2; lsw[t][3] = geo[0] * wgt;
        }
        __syncthreads();

        // ---- phase 1: fc1 + CBN1 in D-layout; init_h in regs; relu->LDS bf16 ----
        f32x4 inith[4][2];
        #pragma unroll
        for (int mt = 0; mt < 4; ++mt) {
            #pragma unroll
            for (int r = 0; r < 4; ++r) {
                const int row = mt * 16 + q * 4 + r;
                const f32x4 lsr = *(const f32x4*)&lsw[row][0];
                #pragma unroll
                for (int nt = 0; nt < 2; ++nt) {
                    const float h0 = fmaf(lsr[0], fw0[nt],
                                     fmaf(lsr[1], fw1[nt],
                                     fmaf(lsr[2], fw2[nt], fb[nt])));
                    const float h1 = fmaf(g1p[nt], h0, b1p[nt]);
                    inith[mt][nt][r] = h1;
                    const int col2 = (w * 32 + nt * 16 + li) * 2;
                    *(short*)((char*)act + row * 256 + (col2 ^ ((row & 7) << 4))) =
                        f2bf(fmaxf(h1, 0.f));
                }
            }
        }
        __syncthreads();

        // ---- GEMM1 ----
        f32x4 acc[4][2];
        #pragma unroll
        for (int mt = 0; mt < 4; ++mt)
            #pragma unroll
            for (int nt = 0; nt < 2; ++nt) {
                acc[mt][nt][0] = r1b[nt]; acc[mt][nt][1] = r1b[nt];
                acc[mt][nt][2] = r1b[nt]; acc[mt][nt][3] = r1b[nt];
            }
        #pragma unroll
        for (int ks = 0; ks < 4; ++ks) {
            short8 a[4];
            #pragma unroll
            for (int mt = 0; mt < 4; ++mt) {
                const int row = mt * 16 + li;
                a[mt] = *(const short8*)((const char*)act +
                        row * 256 + ((ks * 64 + q * 16) ^ ((row & 7) << 4)));
            }
            #pragma unroll
            for (int mt = 0; mt < 4; ++mt)
                #pragma unroll
                for (int nt = 0; nt < 2; ++nt)
                    acc[mt][nt] = __builtin_amdgcn_mfma_f32_16x16x32_bf16(
                        a[mt], bfA[nt][ks], acc[mt][nt], 0, 0, 0);
        }
        __syncthreads();   // all GEMM1 A-reads done before overwrite

        // ---- CBN2 + relu -> LDS bf16 ----
        #pragma unroll
        for (int mt = 0; mt < 4; ++mt)
            #pragma unroll
            for (int r = 0; r < 4; ++r) {
                const int row = mt * 16 + q * 4 + r;
                #pragma unroll
                for (int nt = 0; nt < 2; ++nt) {
                    const float h2 = fmaf(g2p[nt], acc[mt][nt][r], b2p[nt]);
                    const int col2 = (w * 32 + nt * 16 + li) * 2;
                    *(short*)((char*)act + row * 256 + (col2 ^ ((row & 7) << 4))) =
                        f2bf(fmaxf(h2, 0.f));
                }
            }
        __syncthreads();

        // ---- GEMM2 (C-init = init_h + rfc2_b -> D = final h pre-CBN3) ----
        #pragma unroll
        for (int mt = 0; mt < 4; ++mt)
            #pragma unroll
            for (int nt = 0; nt < 2; ++nt) {
                acc[mt][nt][0] = inith[mt][nt][0] + r2b[nt];
                acc[mt][nt][1] = inith[mt][nt][1] + r2b[nt];
                acc[mt][nt][2] = inith[mt][nt][2] + r2b[nt];
                acc[mt][nt][3] = inith[mt][nt][3] + r2b[nt];
            }
        #pragma unroll
        for (int ks = 0; ks < 4; ++ks) {
            short8 a[4];
            #pragma unroll
            for (int mt = 0; mt < 4; ++mt) {
                const int row = mt * 16 + li;
                a[mt] = *(const short8*)((const char*)act +
                        row * 256 + ((ks * 64 + q * 16) ^ ((row & 7) << 4)));
            }
            #pragma unroll
            for (int mt = 0; mt < 4; ++mt)
                #pragma unroll
                for (int nt = 0; nt < 2; ++nt)
                    acc[mt][nt] = __builtin_amdgcn_mfma_f32_16x16x32_bf16(
                        a[mt], bfB[nt][ks], acc[mt][nt], 0, 0, 0);
        }

        // ---- epilogue: val = sum_col g3w*h + cbeta, per-row reduce ----
        #pragma unroll
        for (int mt = 0; mt < 4; ++mt)
            #pragma unroll
            for (int r = 0; r < 4; ++r) {
                float p = fmaf(g3w[0], acc[mt][0][r], g3w[1] * acc[mt][1][r]);
                p += __shfl_xor(p, 1);
                p += __shfl_xor(p, 2);
                p += __shfl_xor(p, 4);
                p += __shfl_xor(p, 8);
                if (li == 0) red[mt * 16 + q * 4 + r][w] = p;
            }
        __syncthreads();

        if (t < 64) {
            const float val = red[t][0] + red[t][1] + red[t][2] + red[t][3] + cbeta;
            const float contrib = lsw[t][3] * (1.f + val);
            atomicAdd(&out[(size_t)b * S_ + sbase + t], contrib);
        }
        __syncthreads();   // red/act safe for next tile
    }
}

// ---------------------------------------------------------------------------
extern "C" void kernel_launch(void* const* d_in, const int* in_sizes, int n_in,
                              void* d_out, int out_size, void* d_ws, size_t ws_size,
                              hipStream_t stream) {
    (void)in_sizes; (void)n_in; (void)d_ws; (void)ws_size;

    const float* packed  = (const float*)d_in[0];
    const float* samples = (const float*)d_in[1];
    const float* fc1w = (const float*)d_in[2];
    const float* fc1b = (const float*)d_in[3];
    const float* bw1  = (const float*)d_in[4];
    const float* bb1  = (const float*)d_in[5];
    const float* gw1  = (const float*)d_in[6];
    const float* gb1  = (const float*)d_in[7];
    const float* rw1  = (const float*)d_in[8];
    const float* rb1  = (const float*)d_in[9];
    const float* bw2  = (const float*)d_in[10];
    const float* bb2  = (const float*)d_in[11];
    const float* gw2  = (const float*)d_in[12];
    const float* gb2  = (const float*)d_in[13];
    const float* rw2  = (const float*)d_in[14];
    const float* rb2  = (const float*)d_in[15];
    const float* bw3  = (const float*)d_in[16];
    const float* bb3  = (const float*)d_in[17];
    const float* gw3  = (const float*)d_in[18];
    const float* gb3  = (const float*)d_in[19];
    const float* fc2w = (const float*)d_in[20];
    const float* fc2b = (const float*)d_in[21];
    float* out = (float*)d_out;

    hipMemsetAsync(out, 0, (size_t)out_size * sizeof(float), stream);

    prep_weights<<<64, 64, 0, stream>>>(rw1, rw2);

    precompute_kernel<<<B_ * E_, 128, 0, stream>>>(
        packed, bw1, bb1, gw1, gb1, bw2, bb2, gw2, gb2, bw3, bb3, gw3, gb3,
        fc2w, fc2b);

    ldif_mfma<<<B_ * E_ * NST_, 256, 0, stream>>>(
        samples, fc1w, fc1b, rb1, rb2, out);
}

// Round 4
// 41.933 us; speedup vs baseline: 7.4832x; 2.1391x over previous
//
#include <hip/hip_runtime.h>
#include <math.h>

#define B_   4
#define EC_  32
#define E_   48
#define S_   2048
#define F_   128

typedef __attribute__((ext_vector_type(8)))  short short8;
typedef __attribute__((ext_vector_type(4)))  float f32x4;
typedef __attribute__((ext_vector_type(16))) float f32x16;

// ---- global prepacked parameter parks -------------------------------------
// A1: GEMM1 weights (rfc1_w) as 32x32x16 A-fragments, transposed GEMM:
//   A1frag[MT][ks][lane][j] = bf16( rw1[f_in][f_out] )
//   f_out = MT*32 + (lane&31)
//   f_in  = (ks>>1)*32 + (ks&1)*16 + ((j>>2)&1)*8 + (j&3) + (lane>>5)*4
__device__ __align__(16) short g_A1[4 * 8 * 64 * 8];     // 32 KB

// per-be park (floats): [0..127]=gamma2', [128..255]=beta2', [256..383]=u,
// [384..511]=g3w, [512..527]=geo, [528]=cbeta', [544..1567]=A0 frags (shorts)
#define PKF 1568
__device__ __align__(16) float g_bepark[B_ * E_ * PKF];

static __device__ __forceinline__ short f2bf(float x) {
    unsigned u = __float_as_uint(x);
    unsigned r = (u + 0x7FFFu + ((u >> 16) & 1u)) >> 16;   // RNE
    return (short)r;
}

// ---------------------------------------------------------------------------
// Kernel A: pack rfc1_w into A1 fragments. grid = 32 (MT*8+ks) x 64 threads
// ---------------------------------------------------------------------------
__global__ __launch_bounds__(64) void prep_A1(const float* __restrict__ rw1)
{
    const int MT = blockIdx.x >> 3;
    const int ks = blockIdx.x & 7;
    const int l  = threadIdx.x;
    const int fo = MT * 32 + (l & 31);
    const int q1 = l >> 5;
    short8 v;
    #pragma unroll
    for (int j = 0; j < 8; ++j) {
        const int fi = (ks >> 1) * 32 + (ks & 1) * 16 + ((j >> 2) & 1) * 8 +
                       (j & 3) + q1 * 4;
        v[j] = f2bf(rw1[fi * F_ + fo]);
    }
    *(short8*)&g_A1[((MT * 8 + ks) * 64 + l) * 8] = v;
}

// ---------------------------------------------------------------------------
// Kernel B: per-(b,e) CBN GEMVs + folds + A0 frags + geometry.
// grid = 192 x 256 threads (t = feature, h = k-half for split-k GEMV)
// ---------------------------------------------------------------------------
__global__ __launch_bounds__(256) void precompute_kernel(
    const float* __restrict__ packed,
    const float* __restrict__ fc1w, const float* __restrict__ fc1b,
    const float* __restrict__ bw1, const float* __restrict__ bb1,
    const float* __restrict__ gw1, const float* __restrict__ gb1,
    const float* __restrict__ rb1g,
    const float* __restrict__ bw2, const float* __restrict__ bb2,
    const float* __restrict__ gw2, const float* __restrict__ gb2,
    const float* __restrict__ rw2, const float* __restrict__ rb2g,
    const float* __restrict__ bw3, const float* __restrict__ bb3,
    const float* __restrict__ gw3, const float* __restrict__ gb3,
    const float* __restrict__ fc2w, const float* __restrict__ fc2b)
{
    const int be = blockIdx.x;
    const int b  = be / E_;
    const int e  = be - b * E_;
    const int ec = (e < EC_) ? e : (e - EC_);
    const float* pv = packed + (size_t)(b * EC_ + ec) * 138;
    float* P = g_bepark + (size_t)be * PKF;

    __shared__ float emb[F_];
    __shared__ float part[6][2][F_];
    __shared__ float g3s[F_];
    __shared__ float redbuf[F_];

    const int t = threadIdx.x & 127;
    const int h = threadIdx.x >> 7;
    if (h == 0) emb[t] = pv[10 + t];
    __syncthreads();

    float a0 = 0.f, a1 = 0.f, a2 = 0.f, a3 = 0.f, a4 = 0.f, a5 = 0.f;
    for (int k = h * 64; k < h * 64 + 64; ++k) {
        const float ek = emb[k];
        a0 = fmaf(ek, bw1[k * F_ + t], a0);
        a1 = fmaf(ek, gw1[k * F_ + t], a1);
        a2 = fmaf(ek, bw2[k * F_ + t], a2);
        a3 = fmaf(ek, gw2[k * F_ + t], a3);
        a4 = fmaf(ek, bw3[k * F_ + t], a4);
        a5 = fmaf(ek, gw3[k * F_ + t], a5);
    }
    part[0][h][t] = a0; part[1][h][t] = a1; part[2][h][t] = a2;
    part[3][h][t] = a3; part[4][h][t] = a4; part[5][h][t] = a5;
    __syncthreads();

    const float inv = 0.99999500003749984f;   // 1/sqrt(1+1e-5)
    if (h == 0) {
        const float sb1 = part[0][0][t] + part[0][1][t];
        const float sg1 = part[1][0][t] + part[1][1][t];
        const float sb2 = part[2][0][t] + part[2][1][t];
        const float sg2 = part[3][0][t] + part[3][1][t];
        const float sb3 = part[4][0][t] + part[4][1][t];
        const float sg3 = part[5][0][t] + part[5][1][t];

        const float g1p = (sg1 + gb1[t]) * inv;
        const float b1  =  sb1 + bb1[t];
        const float g2p = (sg2 + gb2[t]) * inv;
        const float b2p = fmaf(g2p, rb1g[t], sb2 + bb2[t]);   // rb1 folded
        const float g3  = (sg3 + gb3[t]) * inv * fc2w[t];     // fc2 folded

        P[0 * F_ + t] = g2p;
        P[1 * F_ + t] = b2p;
        P[3 * F_ + t] = g3;
        g3s[t] = g3;
        redbuf[t] = (sb3 + bb3[t]) * fc2w[t] + g3 * rb2g[t];  // beta3+rb2 fold

        // A0 fragment (fc1 + CBN1 folded), 32x32x16 A-layout, k slots 0..3
        const float w0p = g1p * fc1w[t];
        const float w1p = g1p * fc1w[F_ + t];
        const float w2p = g1p * fc1w[2 * F_ + t];
        const float pbp = fmaf(g1p, fc1b[t], b1);
        short* A0 = (short*)(P + 544);
        const int MTl = t >> 5, fl = t & 31;
        short8 v  = {f2bf(w0p), f2bf(w1p), f2bf(w2p), f2bf(pbp), 0, 0, 0, 0};
        short8 zz = {0, 0, 0, 0, 0, 0, 0, 0};
        *(short8*)&A0[(MTl * 64 + fl) * 8]      = v;
        *(short8*)&A0[(MTl * 64 + 32 + fl) * 8] = zz;
    }
    __syncthreads();

    // u[k] = sum_f g3w[f] * rw2[k][f]   (split over h)
    {
        float ua = 0.f;
        const float* wrow = rw2 + (size_t)t * F_ + h * 64;
        #pragma unroll
        for (int f4 = 0; f4 < 64; f4 += 4) {
            const f32x4 wv = *(const f32x4*)&wrow[f4];
            const int fb = h * 64 + f4;
            ua = fmaf(wv[0], g3s[fb + 0], ua);
            ua = fmaf(wv[1], g3s[fb + 1], ua);
            ua = fmaf(wv[2], g3s[fb + 2], ua);
            ua = fmaf(wv[3], g3s[fb + 3], ua);
        }
        part[0][h][t] = ua;
    }
    __syncthreads();
    if (h == 0) P[2 * F_ + t] = part[0][0][t] + part[0][1][t];

    if (threadIdx.x == 0) {
        float cb = fc2b[0];
        for (int i = 0; i < F_; ++i) cb += redbuf[i];
        P[528] = cb;

        const float sx = fmaxf(pv[4], 1e-4f);
        const float sy = fmaxf(pv[5], 1e-4f);
        const float sz = fmaxf(pv[6], 1e-4f);
        const float ar = pv[7], ap = pv[8], ay = pv[9];
        const float cr = cosf(ar), sr = sinf(ar);
        const float cp = cosf(ap), sp = sinf(ap);
        const float cyw = cosf(ay), syw = sinf(ay);
        float* g = P + 512;
        g[0] = pv[0]; g[1] = pv[1]; g[2] = pv[2]; g[3] = pv[3];
        g[4] = 1.f / sx; g[5] = 1.f / sy; g[6] = 1.f / sz;
        g[7]  = cyw * cp;  g[8]  = cyw * sp * sr - syw * cr;  g[9]  = cyw * sp * cr + syw * sr;
        g[10] = syw * cp;  g[11] = syw * sp * sr + cyw * cr;  g[12] = syw * sp * cr - cyw * sr;
        g[13] = -sp;       g[14] = cp * sr;                   g[15] = cp * cr;
    }
}

// ---------------------------------------------------------------------------
// Kernel C: main. grid = 192*8 = 1536 WGs x 256 threads (4 indep waves).
// Wave handles 32 samples/pass, 2 passes. Register-resident activation chain:
// fc1-MFMA (4x 32x32x16) -> in-reg relu/cvt repack -> GEMM1 (32 MFMA) ->
// in-reg CBN2 + dual dot epilogue. No barriers in the pass loop.
// ---------------------------------------------------------------------------
__global__ __launch_bounds__(256, 2) void ldif_main(
    const float* __restrict__ samples, float* __restrict__ out)
{
    const int bid = blockIdx.x;
    const int be  = bid >> 3;
    const int seg = bid & 7;
    const int b   = be / E_;
    const int e   = be - b * E_;
    const bool zflip = (e >= EC_);

    __shared__ __align__(16) short lsA1[4 * 8 * 64 * 8];   // 32 KB
    __shared__ __align__(16) short lsA0[4 * 64 * 8];       // 4 KB
    __shared__ __align__(16) float lsG2[F_], lsB2[F_], lsU[F_], lsG3[F_];
    __shared__ __align__(16) float lsGeo[20];

    const int tid = threadIdx.x;

    // ---- stage weights/params into LDS (all reads later are conflict-free)
    {
        const f32x4* src = (const f32x4*)g_A1;
        f32x4* dst = (f32x4*)lsA1;
        #pragma unroll
        for (int i = 0; i < 8; ++i) dst[i * 256 + tid] = src[i * 256 + tid];
    }
    {
        const float* P = g_bepark + (size_t)be * PKF;
        if (tid < 128) {
            const f32x4 v = *(const f32x4*)&P[tid * 4];
            const int a = tid >> 5, i = (tid & 31) * 4;
            if      (a == 0) *(f32x4*)&lsG2[i] = v;
            else if (a == 1) *(f32x4*)&lsB2[i] = v;
            else if (a == 2) *(f32x4*)&lsU[i]  = v;
            else             *(f32x4*)&lsG3[i] = v;
        } else if (tid < 192) {
            const int c = tid - 128;
            float* a0f = (float*)lsA0;
            #pragma unroll
            for (int i = 0; i < 4; ++i)
                *(f32x4*)&a0f[(i * 64 + c) * 4] = *(const f32x4*)&P[544 + (i * 64 + c) * 4];
        } else if (tid < 197) {
            const int c = tid - 192;
            *(f32x4*)&lsGeo[c * 4] = *(const f32x4*)&P[512 + c * 4];
        }
    }
    __syncthreads();

    const int l   = tid & 63;
    const int w   = tid >> 6;
    const int q1  = l >> 5;
    const int l31 = l & 31;
    const f32x16 z16 = {0.f,0.f,0.f,0.f,0.f,0.f,0.f,0.f,
                        0.f,0.f,0.f,0.f,0.f,0.f,0.f,0.f};

    #pragma unroll
    for (int pass = 0; pass < 2; ++pass) {
        const int s = seg * 256 + pass * 128 + w * 32 + l31;

        // ---- geometry (all lanes compute; q1==1 supplies zero B0) ----
        float cwgt;
        union { short8 s8; unsigned u[4]; } b0u;
        b0u.u[0] = 0; b0u.u[1] = 0; b0u.u[2] = 0; b0u.u[3] = 0;
        {
            const float* sp = samples + ((size_t)b * S_ + s) * 3;
            float x = sp[0], y = sp[1], z = sp[2];
            if (zflip) z = -z;
            const float dx = x - lsGeo[1], dy = y - lsGeo[2], dz = z - lsGeo[3];
            const float l0 = (dx * lsGeo[7] + dy * lsGeo[10] + dz * lsGeo[13]) * lsGeo[4];
            const float l1 = (dx * lsGeo[8] + dy * lsGeo[11] + dz * lsGeo[14]) * lsGeo[5];
            const float l2 = (dx * lsGeo[9] + dy * lsGeo[12] + dz * lsGeo[15]) * lsGeo[6];
            cwgt = lsGeo[0] * __expf(-0.5f * (l0 * l0 + l1 * l1 + l2 * l2));
            if (q1 == 0) {
                const float one = 1.0f;
                unsigned p01, p23;
                asm("v_cvt_pk_bf16_f32 %0, %1, %2" : "=v"(p01) : "v"(l0), "v"(l1));
                asm("v_cvt_pk_bf16_f32 %0, %1, %2" : "=v"(p23) : "v"(l2), "v"(one));
                b0u.u[0] = p01; b0u.u[1] = p23;
            }
        }
        const short8 b0 = b0u.s8;

        // ---- fc1 + CBN1 via MFMA: d0[MT] = h1[f][s] (init_h) ----
        f32x16 d0[4];
        #pragma unroll
        for (int MT = 0; MT < 4; ++MT) {
            const short8 a0 = *(const short8*)&lsA0[(MT * 64 + l) * 8];
            d0[MT] = __builtin_amdgcn_mfma_f32_32x32x16_bf16(a0, b0, z16, 0, 0, 0);
        }

        // ---- GEMM1: d1 = relu(h1) @ W1 (transposed, in-reg B repack) ----
        f32x16 d1[4];
        #pragma unroll
        for (int MT = 0; MT < 4; ++MT) d1[MT] = z16;
        #pragma unroll
        for (int ks = 0; ks < 8; ++ks) {
            union { short8 s8; unsigned u[4]; } b1u;
            #pragma unroll
            for (int jj = 0; jj < 4; ++jj) {
                const int j0 = jj * 2;
                const int r0 = (j0 & 3) + 4 * ((j0 >> 2) & 1) + 8 * (ks & 1);
                const float v0 = fmaxf(d0[ks >> 1][r0], 0.f);
                const float v1 = fmaxf(d0[ks >> 1][r0 + 1], 0.f);
                asm("v_cvt_pk_bf16_f32 %0, %1, %2" : "=v"(b1u.u[jj]) : "v"(v0), "v"(v1));
            }
            const short8 b1 = b1u.s8;
            #pragma unroll
            for (int MT = 0; MT < 4; ++MT) {
                const short8 a = *(const short8*)&lsA1[((MT * 8 + ks) * 64 + l) * 8];
                d1[MT] = __builtin_amdgcn_mfma_f32_32x32x16_bf16(a, b1, d1[MT], 0, 0, 0);
            }
        }

        // ---- epilogue: val = sum_f g3w*h1 + sum_k relu(g2*d1+b2')*u + cb ----
        float part = 0.f;
        #pragma unroll
        for (int MT = 0; MT < 4; ++MT) {
            #pragma unroll
            for (int c = 0; c < 4; ++c) {
                const int fb = MT * 32 + c * 8 + q1 * 4;
                const f32x4 g2 = *(const f32x4*)&lsG2[fb];
                const f32x4 b2 = *(const f32x4*)&lsB2[fb];
                const f32x4 uu = *(const f32x4*)&lsU[fb];
                const f32x4 g3 = *(const f32x4*)&lsG3[fb];
                #pragma unroll
                for (int i = 0; i < 4; ++i) {
                    const int r = c * 4 + i;
                    part = fmaf(g3[i], d0[MT][r], part);
                    const float tt = fmaf(g2[i], d1[MT][r], b2[i]);
                    part = fmaf(fmaxf(tt, 0.f), uu[i], part);
                }
            }
        }
        part += __shfl_xor(part, 32);
        if (l < 32) {
            const float val = part + lsGeo[16];
            atomicAdd(&out[(size_t)b * S_ + s], cwgt * (1.f + val));
        }
    }
}

// ---------------------------------------------------------------------------
extern "C" void kernel_launch(void* const* d_in, const int* in_sizes, int n_in,
                              void* d_out, int out_size, void* d_ws, size_t ws_size,
                              hipStream_t stream) {
    (void)in_sizes; (void)n_in; (void)d_ws; (void)ws_size;

    const float* packed  = (const float*)d_in[0];
    const float* samples = (const float*)d_in[1];
    const float* fc1w = (const float*)d_in[2];
    const float* fc1b = (const float*)d_in[3];
    const float* bw1  = (const float*)d_in[4];
    const float* bb1  = (const float*)d_in[5];
    const float* gw1  = (const float*)d_in[6];
    const float* gb1  = (const float*)d_in[7];
    const float* rw1  = (const float*)d_in[8];
    const float* rb1  = (const float*)d_in[9];
    const float* bw2  = (const float*)d_in[10];
    const float* bb2  = (const float*)d_in[11];
    const float* gw2  = (const float*)d_in[12];
    const float* gb2  = (const float*)d_in[13];
    const float* rw2  = (const float*)d_in[14];
    const float* rb2  = (const float*)d_in[15];
    const float* bw3  = (const float*)d_in[16];
    const float* bb3  = (const float*)d_in[17];
    const float* gw3  = (const float*)d_in[18];
    const float* gb3  = (const float*)d_in[19];
    const float* fc2w = (const float*)d_in[20];
    const float* fc2b = (const float*)d_in[21];
    float* out = (float*)d_out;

    (void)hipMemsetAsync(out, 0, (size_t)out_size * sizeof(float), stream);

    prep_A1<<<32, 64, 0, stream>>>(rw1);

    precompute_kernel<<<B_ * E_, 256, 0, stream>>>(
        packed, fc1w, fc1b,
        bw1, bb1, gw1, gb1, rb1,
        bw2, bb2, gw2, gb2, rw2, rb2,
        bw3, bb3, gw3, gb3, fc2w, fc2b);

    ldif_main<<<B_ * E_ * 8, 256, 0, stream>>>(samples, out);
}

// Round 5
// 39.298 us; speedup vs baseline: 7.9850x; 1.0671x over previous
//
#include <hip/hip_runtime.h>
#include <math.h>

#define B_   4
#define EC_  32
#define E_   48
#define S_   2048
#define F_   128

typedef __attribute__((ext_vector_type(8)))  short short8;
typedef __attribute__((ext_vector_type(4)))  float f32x4;
typedef __attribute__((ext_vector_type(16))) float f32x16;

// ---- global prepacked parameter parks -------------------------------------
// A1: GEMM1 weights (rfc1_w) as 32x32x16 A-fragments, transposed GEMM:
//   A1frag[MT][ks][lane][j] = bf16( rw1[f_in][f_out] )
//   f_out = MT*32 + (lane&31)
//   f_in  = (ks>>1)*32 + (ks&1)*16 + ((j>>2)&1)*8 + (j&3) + (lane>>5)*4
__device__ __align__(16) short g_A1[4 * 8 * 64 * 8];     // 32 KB

// per-be park (floats):
// [0..127]=gamma2', [128..255]=beta2', [256..383]=u, [384..399]=geo,
// [400..403]=w3c (w3[0..2], w3b+cbeta), [416..1439]=A0 frags (2048 shorts)
#define PKF2 1440
__device__ __align__(16) float g_bepark[B_ * E_ * PKF2];

static __device__ __forceinline__ short f2bf(float x) {
    unsigned u = __float_as_uint(x);
    unsigned r = (u + 0x7FFFu + ((u >> 16) & 1u)) >> 16;   // RNE
    return (short)r;
}

// ---------------------------------------------------------------------------
// Kernel A: per-(b,e) CBN GEMVs + folds + A0 frags + geometry (blocks 0..191)
// and rfc1_w -> A1 fragment packing (blocks 192..199).
// grid = 200 x 256 threads
// ---------------------------------------------------------------------------
__global__ __launch_bounds__(256) void precompute_kernel(
    const float* __restrict__ packed,
    const float* __restrict__ fc1w, const float* __restrict__ fc1b,
    const float* __restrict__ bw1, const float* __restrict__ bb1,
    const float* __restrict__ gw1, const float* __restrict__ gb1,
    const float* __restrict__ rb1g, const float* __restrict__ rw1,
    const float* __restrict__ bw2, const float* __restrict__ bb2,
    const float* __restrict__ gw2, const float* __restrict__ gb2,
    const float* __restrict__ rw2, const float* __restrict__ rb2g,
    const float* __restrict__ bw3, const float* __restrict__ bb3,
    const float* __restrict__ gw3, const float* __restrict__ gb3,
    const float* __restrict__ fc2w, const float* __restrict__ fc2b)
{
    const int be = blockIdx.x;

    if (be >= 192) {                       // ---- A1 packing path ----
        const int unit = (be - 192) * 4 + (threadIdx.x >> 6);   // 0..31
        const int l  = threadIdx.x & 63;
        const int MT = unit >> 3;
        const int ks = unit & 7;
        const int fo = MT * 32 + (l & 31);
        const int q1 = l >> 5;
        short8 v;
        #pragma unroll
        for (int j = 0; j < 8; ++j) {
            const int fi = (ks >> 1) * 32 + (ks & 1) * 16 + ((j >> 2) & 1) * 8 +
                           (j & 3) + q1 * 4;
            v[j] = f2bf(rw1[fi * F_ + fo]);
        }
        *(short8*)&g_A1[((MT * 8 + ks) * 64 + l) * 8] = v;
        return;
    }

    const int b  = be / E_;
    const int e  = be - b * E_;
    const int ec = (e < EC_) ? e : (e - EC_);
    const float* pv = packed + (size_t)(b * EC_ + ec) * 138;
    float* P = g_bepark + (size_t)be * PKF2;

    __shared__ float emb[F_];
    __shared__ float part[6][2][F_];
    __shared__ float g3s[F_];
    __shared__ float redbuf[F_];

    const int t = threadIdx.x & 127;
    const int h = threadIdx.x >> 7;
    if (h == 0) emb[t] = pv[10 + t];
    __syncthreads();

    float a0 = 0.f, a1 = 0.f, a2 = 0.f, a3 = 0.f, a4 = 0.f, a5 = 0.f;
    for (int k = h * 64; k < h * 64 + 64; ++k) {
        const float ek = emb[k];
        a0 = fmaf(ek, bw1[k * F_ + t], a0);
        a1 = fmaf(ek, gw1[k * F_ + t], a1);
        a2 = fmaf(ek, bw2[k * F_ + t], a2);
        a3 = fmaf(ek, gw2[k * F_ + t], a3);
        a4 = fmaf(ek, bw3[k * F_ + t], a4);
        a5 = fmaf(ek, gw3[k * F_ + t], a5);
    }
    part[0][h][t] = a0; part[1][h][t] = a1; part[2][h][t] = a2;
    part[3][h][t] = a3; part[4][h][t] = a4; part[5][h][t] = a5;
    __syncthreads();

    const float inv = 0.99999500003749984f;   // 1/sqrt(1+1e-5)
    if (h == 0) {
        const float sb1 = part[0][0][t] + part[0][1][t];
        const float sg1 = part[1][0][t] + part[1][1][t];
        const float sb2 = part[2][0][t] + part[2][1][t];
        const float sg2 = part[3][0][t] + part[3][1][t];
        const float sb3 = part[4][0][t] + part[4][1][t];
        const float sg3 = part[5][0][t] + part[5][1][t];

        const float g1p = (sg1 + gb1[t]) * inv;
        const float b1  =  sb1 + bb1[t];
        const float g2p = (sg2 + gb2[t]) * inv;
        const float b2p = fmaf(g2p, rb1g[t], sb2 + bb2[t]);   // rb1 folded
        const float g3  = (sg3 + gb3[t]) * inv * fc2w[t];     // fc2 folded

        P[0 * F_ + t] = g2p;
        P[1 * F_ + t] = b2p;
        g3s[t] = g3;
        redbuf[t] = (sb3 + bb3[t]) * fc2w[t] + g3 * rb2g[t];  // beta3+rb2 fold

        // A0 fragment (fc1 + CBN1 folded), 32x32x16 A-layout, k slots 0..3
        const float w0p = g1p * fc1w[t];
        const float w1p = g1p * fc1w[F_ + t];
        const float w2p = g1p * fc1w[2 * F_ + t];
        const float pbp = fmaf(g1p, fc1b[t], b1);
        short* A0 = (short*)(P + 416);
        const int MTl = t >> 5, fl = t & 31;
        short8 v  = {f2bf(w0p), f2bf(w1p), f2bf(w2p), f2bf(pbp), 0, 0, 0, 0};
        short8 zz = {0, 0, 0, 0, 0, 0, 0, 0};
        *(short8*)&A0[(MTl * 64 + fl) * 8]      = v;
        *(short8*)&A0[(MTl * 64 + 32 + fl) * 8] = zz;

        // w3 partial products (exact fp32 fold of g3 . h1)
        part[1][0][t] = g3 * w0p;
        part[2][0][t] = g3 * w1p;
        part[3][0][t] = g3 * w2p;
        part[4][0][t] = g3 * pbp;
    }
    __syncthreads();

    // u[k] = sum_f g3[f] * rw2[k][f]   (split over h)
    {
        float ua = 0.f;
        const float* wrow = rw2 + (size_t)t * F_ + h * 64;
        #pragma unroll
        for (int f4 = 0; f4 < 64; f4 += 4) {
            const f32x4 wv = *(const f32x4*)&wrow[f4];
            const int fb = h * 64 + f4;
            ua = fmaf(wv[0], g3s[fb + 0], ua);
            ua = fmaf(wv[1], g3s[fb + 1], ua);
            ua = fmaf(wv[2], g3s[fb + 2], ua);
            ua = fmaf(wv[3], g3s[fb + 3], ua);
        }
        part[0][h][t] = ua;
    }
    __syncthreads();
    if (h == 0) P[2 * F_ + t] = part[0][0][t] + part[0][1][t];

    if (threadIdx.x == 0) {
        float cb = fc2b[0];
        float w30 = 0.f, w31 = 0.f, w32 = 0.f, w3b = 0.f;
        for (int i = 0; i < F_; ++i) {
            cb  += redbuf[i];
            w30 += part[1][0][i];
            w31 += part[2][0][i];
            w32 += part[3][0][i];
            w3b += part[4][0][i];
        }
        P[400] = w30; P[401] = w31; P[402] = w32; P[403] = w3b + cb;

        const float sx = fmaxf(pv[4], 1e-4f);
        const float sy = fmaxf(pv[5], 1e-4f);
        const float sz = fmaxf(pv[6], 1e-4f);
        const float ar = pv[7], ap = pv[8], ay = pv[9];
        const float cr = cosf(ar), sr = sinf(ar);
        const float cp = cosf(ap), sp = sinf(ap);
        const float cyw = cosf(ay), syw = sinf(ay);
        float* g = P + 384;
        g[0] = pv[0]; g[1] = pv[1]; g[2] = pv[2]; g[3] = pv[3];
        g[4] = 1.f / sx; g[5] = 1.f / sy; g[6] = 1.f / sz;
        g[7]  = cyw * cp;  g[8]  = cyw * sp * sr - syw * cr;  g[9]  = cyw * sp * cr + syw * sr;
        g[10] = syw * cp;  g[11] = syw * sp * sr + cyw * cr;  g[12] = syw * sp * cr - cyw * sr;
        g[13] = -sp;       g[14] = cp * sr;                   g[15] = cp * cr;
    }
}

// ---------------------------------------------------------------------------
// Kernel B: main. grid = 4b x 16seg x 8eg = 512 WGs x 256 threads (4 waves).
// Each wave owns 32 samples and loops 6 elements, accumulating the SDF
// contribution in a register; one atomicAdd per sample at the end (8-way).
// ---------------------------------------------------------------------------
__global__ __launch_bounds__(256, 2) void ldif_main(
    const float* __restrict__ samples, float* __restrict__ out)
{
    const int bid = blockIdx.x;
    const int eg  = bid & 7;
    const int seg = (bid >> 3) & 15;
    const int b   = bid >> 7;
    const int be0 = b * E_ + eg * 6;

    __shared__ __align__(16) short lsA1[4 * 8 * 64 * 8];   // 32 KB
    __shared__ __align__(16) float lsPar[6 * 416];         // ~10 KB

    const int tid = threadIdx.x;

    // ---- stage A1 weights + 6 elements' params into LDS ----
    {
        const f32x4* src = (const f32x4*)g_A1;
        f32x4* dst = (f32x4*)lsA1;
        #pragma unroll
        for (int i = 0; i < 8; ++i) dst[i * 256 + tid] = src[i * 256 + tid];
    }
    for (int i = tid; i < 624; i += 256) {
        const int ei = i / 104;
        const int o4 = i - ei * 104;
        ((f32x4*)lsPar)[ei * 104 + o4] =
            *(const f32x4*)&g_bepark[(size_t)(be0 + ei) * PKF2 + o4 * 4];
    }
    __syncthreads();

    const int l   = tid & 63;
    const int w   = tid >> 6;
    const int q1  = l >> 5;
    const int l31 = l & 31;
    const int sidx = seg * 128 + w * 32 + l31;
    const f32x16 z16 = {0.f,0.f,0.f,0.f,0.f,0.f,0.f,0.f,
                        0.f,0.f,0.f,0.f,0.f,0.f,0.f,0.f};

    // sample coords loaded once, reused for all 6 elements
    const float* sp = samples + ((size_t)b * S_ + sidx) * 3;
    const float xs = sp[0], ys = sp[1], zs0 = sp[2];

    float acc = 0.f;

    #pragma unroll
    for (int ee = 0; ee < 6; ++ee) {
        const int pe = ee * 416;
        const float* gg = &lsPar[pe + 384];
        const float* w3 = &lsPar[pe + 400];
        const int e = eg * 6 + ee;

        // ---- geometry ----
        float cwgt, sval;
        union { short8 s8; unsigned u[4]; } b0u;
        b0u.u[0] = 0; b0u.u[1] = 0; b0u.u[2] = 0; b0u.u[3] = 0;
        {
            const float zz = (e >= EC_) ? -zs0 : zs0;
            const float dx = xs - gg[1], dy = ys - gg[2], dz = zz - gg[3];
            const float l0 = (dx * gg[7] + dy * gg[10] + dz * gg[13]) * gg[4];
            const float l1 = (dx * gg[8] + dy * gg[11] + dz * gg[14]) * gg[5];
            const float l2 = (dx * gg[9] + dy * gg[12] + dz * gg[15]) * gg[6];
            cwgt = gg[0] * __expf(-0.5f * (l0 * l0 + l1 * l1 + l2 * l2));
            sval = fmaf(l0, w3[0], fmaf(l1, w3[1], fmaf(l2, w3[2], w3[3])));
            if (q1 == 0) {
                const float one = 1.0f;
                unsigned p01, p23;
                asm("v_cvt_pk_bf16_f32 %0, %1, %2" : "=v"(p01) : "v"(l0), "v"(l1));
                asm("v_cvt_pk_bf16_f32 %0, %1, %2" : "=v"(p23) : "v"(l2), "v"(one));
                b0u.u[0] = p01; b0u.u[1] = p23;
            }
        }
        const short8 b0 = b0u.s8;

        // ---- fc1 + CBN1 via MFMA (A0 frags straight from L2) ----
        const short* A0g = (const short*)(g_bepark + (size_t)(be0 + ee) * PKF2 + 416);
        f32x16 d0[4];
        #pragma unroll
        for (int MT = 0; MT < 4; ++MT) {
            const short8 a0 = *(const short8*)&A0g[(MT * 64 + l) * 8];
            d0[MT] = __builtin_amdgcn_mfma_f32_32x32x16_bf16(a0, b0, z16, 0, 0, 0);
        }

        // ---- GEMM1: d1 = relu(h1) @ W1 (in-reg B repack) ----
        f32x16 d1[4];
        #pragma unroll
        for (int MT = 0; MT < 4; ++MT) d1[MT] = z16;
        #pragma unroll
        for (int ks = 0; ks < 8; ++ks) {
            union { short8 s8; unsigned u[4]; } b1u;
            #pragma unroll
            for (int jj = 0; jj < 4; ++jj) {
                const int j0 = jj * 2;
                const int r0 = (j0 & 3) + 4 * ((j0 >> 2) & 1) + 8 * (ks & 1);
                const float v0 = fmaxf(d0[ks >> 1][r0], 0.f);
                const float v1 = fmaxf(d0[ks >> 1][r0 + 1], 0.f);
                asm("v_cvt_pk_bf16_f32 %0, %1, %2" : "=v"(b1u.u[jj]) : "v"(v0), "v"(v1));
            }
            const short8 b1 = b1u.s8;
            #pragma unroll
            for (int MT = 0; MT < 4; ++MT) {
                const short8 a = *(const short8*)&lsA1[((MT * 8 + ks) * 64 + l) * 8];
                d1[MT] = __builtin_amdgcn_mfma_f32_32x32x16_bf16(a, b1, d1[MT], 0, 0, 0);
            }
        }

        // ---- epilogue: val = sum_k relu(g2*d1+b2')*u  (+ sval) ----
        float part = 0.f;
        #pragma unroll
        for (int MT = 0; MT < 4; ++MT) {
            #pragma unroll
            for (int c = 0; c < 4; ++c) {
                const int fb = MT * 32 + c * 8 + q1 * 4;
                const f32x4 g2 = *(const f32x4*)&lsPar[pe + fb];
                const f32x4 b2 = *(const f32x4*)&lsPar[pe + 128 + fb];
                const f32x4 uu = *(const f32x4*)&lsPar[pe + 256 + fb];
                #pragma unroll
                for (int i = 0; i < 4; ++i) {
                    const float tt = fmaf(g2[i], d1[MT][c * 4 + i], b2[i]);
                    part = fmaf(fmaxf(tt, 0.f), uu[i], part);
                }
            }
        }
        part += __shfl_xor(part, 32);
        acc = fmaf(cwgt, 1.f + part + sval, acc);
    }

    if (l < 32) atomicAdd(&out[(size_t)b * S_ + sidx], acc);
}

// ---------------------------------------------------------------------------
extern "C" void kernel_launch(void* const* d_in, const int* in_sizes, int n_in,
                              void* d_out, int out_size, void* d_ws, size_t ws_size,
                              hipStream_t stream) {
    (void)in_sizes; (void)n_in; (void)d_ws; (void)ws_size;

    const float* packed  = (const float*)d_in[0];
    const float* samples = (const float*)d_in[1];
    const float* fc1w = (const float*)d_in[2];
    const float* fc1b = (const float*)d_in[3];
    const float* bw1  = (const float*)d_in[4];
    const float* bb1  = (const float*)d_in[5];
    const float* gw1  = (const float*)d_in[6];
    const float* gb1  = (const float*)d_in[7];
    const float* rw1  = (const float*)d_in[8];
    const float* rb1  = (const float*)d_in[9];
    const float* bw2  = (const float*)d_in[10];
    const float* bb2  = (const float*)d_in[11];
    const float* gw2  = (const float*)d_in[12];
    const float* gb2  = (const float*)d_in[13];
    const float* rw2  = (const float*)d_in[14];
    const float* rb2  = (const float*)d_in[15];
    const float* bw3  = (const float*)d_in[16];
    const float* bb3  = (const float*)d_in[17];
    const float* gw3  = (const float*)d_in[18];
    const float* gb3  = (const float*)d_in[19];
    const float* fc2w = (const float*)d_in[20];
    const float* fc2b = (const float*)d_in[21];
    float* out = (float*)d_out;

    (void)hipMemsetAsync(out, 0, (size_t)out_size * sizeof(float), stream);

    precompute_kernel<<<200, 256, 0, stream>>>(
        packed, fc1w, fc1b,
        bw1, bb1, gw1, gb1, rb1, rw1,
        bw2, bb2, gw2, gb2, rw2, rb2,
        bw3, bb3, gw3, gb3, fc2w, fc2b);

    ldif_main<<<512, 256, 0, stream>>>(samples, out);
}

// Round 6
// 35.166 us; speedup vs baseline: 8.9233x; 1.1175x over previous
//
#include <hip/hip_runtime.h>
#include <math.h>

#define B_   4
#define EC_  32
#define E_   48
#define S_   2048
#define F_   128

typedef __attribute__((ext_vector_type(8)))  short short8;
typedef __attribute__((ext_vector_type(4)))  float f32x4;
typedef __attribute__((ext_vector_type(16))) float f32x16;

// ---- global prepacked parameter parks -------------------------------------
// A1: GEMM1 weights (rfc1_w) as 32x32x16 A-fragments, transposed GEMM:
//   A1frag[MT][ks][lane][j] = bf16( rw1[f_in][f_out] )
//   f_out = MT*32 + (lane&31)
//   f_in  = (ks>>1)*32 + (ks&1)*16 + ((j>>2)&1)*8 + (j&3) + (lane>>5)*4
__device__ __align__(16) short g_A1[4 * 8 * 64 * 8];     // 32 KB

// per-be park (floats):
// [0..127]=gamma2', [128..255]=beta2', [256..383]=u, [384..399]=geo,
// [400..403]=w3c (w3[0..2], w3b+cbeta), [416..1439]=A0 frags (2048 shorts)
#define PKF2 1440
__device__ __align__(16) float g_bepark[B_ * E_ * PKF2];

static __device__ __forceinline__ short f2bf(float x) {
    unsigned u = __float_as_uint(x);
    unsigned r = (u + 0x7FFFu + ((u >> 16) & 1u)) >> 16;   // RNE
    return (short)r;
}

// ---------------------------------------------------------------------------
// Kernel A: per-(b,e) CBN GEMVs + folds + A0 frags + geometry (blocks 0..191,
// 512 threads: t=feature, h=k-quarter) and rfc1_w -> A1 packing (blocks
// 192..195, 8 units each). grid = 196 x 512
// ---------------------------------------------------------------------------
__global__ __launch_bounds__(512) void precompute_kernel(
    const float* __restrict__ packed,
    const float* __restrict__ fc1w, const float* __restrict__ fc1b,
    const float* __restrict__ bw1, const float* __restrict__ bb1,
    const float* __restrict__ gw1, const float* __restrict__ gb1,
    const float* __restrict__ rb1g, const float* __restrict__ rw1,
    const float* __restrict__ bw2, const float* __restrict__ bb2,
    const float* __restrict__ gw2, const float* __restrict__ gb2,
    const float* __restrict__ rw2, const float* __restrict__ rb2g,
    const float* __restrict__ bw3, const float* __restrict__ bb3,
    const float* __restrict__ gw3, const float* __restrict__ gb3,
    const float* __restrict__ fc2w, const float* __restrict__ fc2b)
{
    const int be = blockIdx.x;

    if (be >= 192) {                       // ---- A1 packing path ----
        const int unit = (be - 192) * 8 + (threadIdx.x >> 6);   // 0..31
        const int l  = threadIdx.x & 63;
        const int MT = unit >> 3;
        const int ks = unit & 7;
        const int fo = MT * 32 + (l & 31);
        const int q1 = l >> 5;
        short8 v;
        #pragma unroll
        for (int j = 0; j < 8; ++j) {
            const int fi = (ks >> 1) * 32 + (ks & 1) * 16 + ((j >> 2) & 1) * 8 +
                           (j & 3) + q1 * 4;
            v[j] = f2bf(rw1[fi * F_ + fo]);
        }
        *(short8*)&g_A1[((MT * 8 + ks) * 64 + l) * 8] = v;
        return;
    }

    const int b  = be / E_;
    const int e  = be - b * E_;
    const int ec = (e < EC_) ? e : (e - EC_);
    const float* pv = packed + (size_t)(b * EC_ + ec) * 138;
    float* P = g_bepark + (size_t)be * PKF2;

    __shared__ float emb[F_];
    __shared__ float part[6][4][F_];     // 12 KB
    __shared__ float g3s[F_];
    __shared__ float redbuf[F_];

    const int t = threadIdx.x & 127;
    const int h = threadIdx.x >> 7;      // 0..3 (k-quarter)
    if (h == 0) emb[t] = pv[10 + t];
    __syncthreads();

    float a0 = 0.f, a1 = 0.f, a2 = 0.f, a3 = 0.f, a4 = 0.f, a5 = 0.f;
    for (int k = h * 32; k < h * 32 + 32; ++k) {
        const float ek = emb[k];
        a0 = fmaf(ek, bw1[k * F_ + t], a0);
        a1 = fmaf(ek, gw1[k * F_ + t], a1);
        a2 = fmaf(ek, bw2[k * F_ + t], a2);
        a3 = fmaf(ek, gw2[k * F_ + t], a3);
        a4 = fmaf(ek, bw3[k * F_ + t], a4);
        a5 = fmaf(ek, gw3[k * F_ + t], a5);
    }
    part[0][h][t] = a0; part[1][h][t] = a1; part[2][h][t] = a2;
    part[3][h][t] = a3; part[4][h][t] = a4; part[5][h][t] = a5;
    __syncthreads();

    const float inv = 0.99999500003749984f;   // 1/sqrt(1+1e-5)
    if (h == 0) {
        const float sb1 = part[0][0][t] + part[0][1][t] + part[0][2][t] + part[0][3][t];
        const float sg1 = part[1][0][t] + part[1][1][t] + part[1][2][t] + part[1][3][t];
        const float sb2 = part[2][0][t] + part[2][1][t] + part[2][2][t] + part[2][3][t];
        const float sg2 = part[3][0][t] + part[3][1][t] + part[3][2][t] + part[3][3][t];
        const float sb3 = part[4][0][t] + part[4][1][t] + part[4][2][t] + part[4][3][t];
        const float sg3 = part[5][0][t] + part[5][1][t] + part[5][2][t] + part[5][3][t];

        const float g1p = (sg1 + gb1[t]) * inv;
        const float b1  =  sb1 + bb1[t];
        const float g2p = (sg2 + gb2[t]) * inv;
        const float b2p = fmaf(g2p, rb1g[t], sb2 + bb2[t]);   // rb1 folded
        const float g3  = (sg3 + gb3[t]) * inv * fc2w[t];     // fc2 folded

        P[0 * F_ + t] = g2p;
        P[1 * F_ + t] = b2p;
        g3s[t] = g3;
        redbuf[t] = (sb3 + bb3[t]) * fc2w[t] + g3 * rb2g[t];  // beta3+rb2 fold

        // A0 fragment (fc1 + CBN1 folded), 32x32x16 A-layout, k slots 0..3
        const float w0p = g1p * fc1w[t];
        const float w1p = g1p * fc1w[F_ + t];
        const float w2p = g1p * fc1w[2 * F_ + t];
        const float pbp = fmaf(g1p, fc1b[t], b1);
        short* A0 = (short*)(P + 416);
        const int MTl = t >> 5, fl = t & 31;
        short8 v  = {f2bf(w0p), f2bf(w1p), f2bf(w2p), f2bf(pbp), 0, 0, 0, 0};
        short8 zz = {0, 0, 0, 0, 0, 0, 0, 0};
        *(short8*)&A0[(MTl * 64 + fl) * 8]      = v;
        *(short8*)&A0[(MTl * 64 + 32 + fl) * 8] = zz;

        // w3 partial products (exact fp32 fold of g3 . h1) -> part[1..4][0]
        part[1][0][t] = g3 * w0p;
        part[2][0][t] = g3 * w1p;
        part[3][0][t] = g3 * w2p;
        part[4][0][t] = g3 * pbp;
    }
    __syncthreads();

    // u[k] = sum_f g3[f] * rw2[k][f]   (split over h quarters) -> part[5]
    {
        float ua = 0.f;
        const float* wrow = rw2 + (size_t)t * F_ + h * 32;
        #pragma unroll
        for (int f4 = 0; f4 < 32; f4 += 4) {
            const f32x4 wv = *(const f32x4*)&wrow[f4];
            const int fb = h * 32 + f4;
            ua = fmaf(wv[0], g3s[fb + 0], ua);
            ua = fmaf(wv[1], g3s[fb + 1], ua);
            ua = fmaf(wv[2], g3s[fb + 2], ua);
            ua = fmaf(wv[3], g3s[fb + 3], ua);
        }
        part[5][h][t] = ua;
    }
    __syncthreads();
    if (h == 0)
        P[2 * F_ + t] = part[5][0][t] + part[5][1][t] + part[5][2][t] + part[5][3][t];

    if (threadIdx.x == 0) {
        float cb = fc2b[0];
        float w30 = 0.f, w31 = 0.f, w32 = 0.f, w3b = 0.f;
        for (int i = 0; i < F_; ++i) {
            cb  += redbuf[i];
            w30 += part[1][0][i];
            w31 += part[2][0][i];
            w32 += part[3][0][i];
            w3b += part[4][0][i];
        }
        P[400] = w30; P[401] = w31; P[402] = w32; P[403] = w3b + cb;

        const float sx = fmaxf(pv[4], 1e-4f);
        const float sy = fmaxf(pv[5], 1e-4f);
        const float sz = fmaxf(pv[6], 1e-4f);
        const float ar = pv[7], ap = pv[8], ay = pv[9];
        const float cr = cosf(ar), sr = sinf(ar);
        const float cp = cosf(ap), sp = sinf(ap);
        const float cyw = cosf(ay), syw = sinf(ay);
        float* g = P + 384;
        g[0] = pv[0]; g[1] = pv[1]; g[2] = pv[2]; g[3] = pv[3];
        g[4] = 1.f / sx; g[5] = 1.f / sy; g[6] = 1.f / sz;
        g[7]  = cyw * cp;  g[8]  = cyw * sp * sr - syw * cr;  g[9]  = cyw * sp * cr + syw * sr;
        g[10] = syw * cp;  g[11] = syw * sp * sr + cyw * cr;  g[12] = syw * sp * cr - cyw * sr;
        g[13] = -sp;       g[14] = cp * sr;                   g[15] = cp * cr;
    }
}

// ---------------------------------------------------------------------------
// Kernel B: main. grid = 4b x 16seg x 8eg = 512 WGs x 256 threads (4 waves).
// Each wave owns 32 samples, loops 6 elements, register accumulator.
// Writes per-eg partial to d_ws (pure store, no atomics, no memset needed).
// ---------------------------------------------------------------------------
__global__ __launch_bounds__(256, 2) void ldif_main(
    const float* __restrict__ samples, float* __restrict__ ws)
{
    const int bid = blockIdx.x;
    const int eg  = bid & 7;
    const int seg = (bid >> 3) & 15;
    const int b   = bid >> 7;
    const int be0 = b * E_ + eg * 6;

    __shared__ __align__(16) short lsA1[4 * 8 * 64 * 8];   // 32 KB
    __shared__ __align__(16) float lsPar[6 * 416];         // ~10 KB

    const int tid = threadIdx.x;

    // ---- stage A1 weights + 6 elements' params into LDS ----
    {
        const f32x4* src = (const f32x4*)g_A1;
        f32x4* dst = (f32x4*)lsA1;
        #pragma unroll
        for (int i = 0; i < 8; ++i) dst[i * 256 + tid] = src[i * 256 + tid];
    }
    for (int i = tid; i < 624; i += 256) {
        const int ei = i / 104;
        const int o4 = i - ei * 104;
        ((f32x4*)lsPar)[ei * 104 + o4] =
            *(const f32x4*)&g_bepark[(size_t)(be0 + ei) * PKF2 + o4 * 4];
    }
    __syncthreads();

    const int l   = tid & 63;
    const int w   = tid >> 6;
    const int q1  = l >> 5;
    const int l31 = l & 31;
    const int sidx = seg * 128 + w * 32 + l31;
    const f32x16 z16 = {0.f,0.f,0.f,0.f,0.f,0.f,0.f,0.f,
                        0.f,0.f,0.f,0.f,0.f,0.f,0.f,0.f};

    // sample coords loaded once, reused for all 6 elements
    const float* sp = samples + ((size_t)b * S_ + sidx) * 3;
    const float xs = sp[0], ys = sp[1], zs0 = sp[2];

    float acc = 0.f;

    #pragma unroll
    for (int ee = 0; ee < 6; ++ee) {
        const int pe = ee * 416;
        const float* gg = &lsPar[pe + 384];
        const float* w3 = &lsPar[pe + 400];
        const int e = eg * 6 + ee;

        // ---- geometry ----
        float cwgt, sval;
        union { short8 s8; unsigned u[4]; } b0u;
        b0u.u[0] = 0; b0u.u[1] = 0; b0u.u[2] = 0; b0u.u[3] = 0;
        {
            const float zz = (e >= EC_) ? -zs0 : zs0;
            const float dx = xs - gg[1], dy = ys - gg[2], dz = zz - gg[3];
            const float l0 = (dx * gg[7] + dy * gg[10] + dz * gg[13]) * gg[4];
            const float l1 = (dx * gg[8] + dy * gg[11] + dz * gg[14]) * gg[5];
            const float l2 = (dx * gg[9] + dy * gg[12] + dz * gg[15]) * gg[6];
            cwgt = gg[0] * __expf(-0.5f * (l0 * l0 + l1 * l1 + l2 * l2));
            sval = fmaf(l0, w3[0], fmaf(l1, w3[1], fmaf(l2, w3[2], w3[3])));
            if (q1 == 0) {
                const float one = 1.0f;
                unsigned p01, p23;
                asm("v_cvt_pk_bf16_f32 %0, %1, %2" : "=v"(p01) : "v"(l0), "v"(l1));
                asm("v_cvt_pk_bf16_f32 %0, %1, %2" : "=v"(p23) : "v"(l2), "v"(one));
                b0u.u[0] = p01; b0u.u[1] = p23;
            }
        }
        const short8 b0 = b0u.s8;

        // ---- fc1 + CBN1 via MFMA (A0 frags straight from L2) ----
        const short* A0g = (const short*)(g_bepark + (size_t)(be0 + ee) * PKF2 + 416);
        f32x16 d0[4];
        #pragma unroll
        for (int MT = 0; MT < 4; ++MT) {
            const short8 a0 = *(const short8*)&A0g[(MT * 64 + l) * 8];
            d0[MT] = __builtin_amdgcn_mfma_f32_32x32x16_bf16(a0, b0, z16, 0, 0, 0);
        }

        // ---- GEMM1: d1 = relu(h1) @ W1 (in-reg B repack) ----
        f32x16 d1[4];
        #pragma unroll
        for (int MT = 0; MT < 4; ++MT) d1[MT] = z16;
        #pragma unroll
        for (int ks = 0; ks < 8; ++ks) {
            union { short8 s8; unsigned u[4]; } b1u;
            #pragma unroll
            for (int jj = 0; jj < 4; ++jj) {
                const int j0 = jj * 2;
                const int r0 = (j0 & 3) + 4 * ((j0 >> 2) & 1) + 8 * (ks & 1);
                const float v0 = fmaxf(d0[ks >> 1][r0], 0.f);
                const float v1 = fmaxf(d0[ks >> 1][r0 + 1], 0.f);
                asm("v_cvt_pk_bf16_f32 %0, %1, %2" : "=v"(b1u.u[jj]) : "v"(v0), "v"(v1));
            }
            const short8 b1 = b1u.s8;
            #pragma unroll
            for (int MT = 0; MT < 4; ++MT) {
                const short8 a = *(const short8*)&lsA1[((MT * 8 + ks) * 64 + l) * 8];
                d1[MT] = __builtin_amdgcn_mfma_f32_32x32x16_bf16(a, b1, d1[MT], 0, 0, 0);
            }
        }

        // ---- epilogue: val = sum_k relu(g2*d1+b2')*u  (+ sval) ----
        float part = 0.f;
        #pragma unroll
        for (int MT = 0; MT < 4; ++MT) {
            #pragma unroll
            for (int c = 0; c < 4; ++c) {
                const int fb = MT * 32 + c * 8 + q1 * 4;
                const f32x4 g2 = *(const f32x4*)&lsPar[pe + fb];
                const f32x4 b2 = *(const f32x4*)&lsPar[pe + 128 + fb];
                const f32x4 uu = *(const f32x4*)&lsPar[pe + 256 + fb];
                #pragma unroll
                for (int i = 0; i < 4; ++i) {
                    const float tt = fmaf(g2[i], d1[MT][c * 4 + i], b2[i]);
                    part = fmaf(fmaxf(tt, 0.f), uu[i], part);
                }
            }
        }
        part += __shfl_xor(part, 32);
        acc = fmaf(cwgt, 1.f + part + sval, acc);
    }

    if (l < 32)
        ws[(size_t)eg * (B_ * S_) + (size_t)b * S_ + sidx] = acc;
}

// ---------------------------------------------------------------------------
// Kernel C: reduce 8 eg-partials per sample -> out (pure store).
// grid = 32 x 256
// ---------------------------------------------------------------------------
__global__ __launch_bounds__(256) void reduce_kernel(
    const float* __restrict__ ws, float* __restrict__ out)
{
    const int i = blockIdx.x * 256 + threadIdx.x;    // 0..8191
    float s = 0.f;
    #pragma unroll
    for (int eg = 0; eg < 8; ++eg)
        s += ws[(size_t)eg * (B_ * S_) + i];
    out[i] = s;
}

// ---------------------------------------------------------------------------
extern "C" void kernel_launch(void* const* d_in, const int* in_sizes, int n_in,
                              void* d_out, int out_size, void* d_ws, size_t ws_size,
                              hipStream_t stream) {
    (void)in_sizes; (void)n_in; (void)out_size; (void)ws_size;

    const float* packed  = (const float*)d_in[0];
    const float* samples = (const float*)d_in[1];
    const float* fc1w = (const float*)d_in[2];
    const float* fc1b = (const float*)d_in[3];
    const float* bw1  = (const float*)d_in[4];
    const float* bb1  = (const float*)d_in[5];
    const float* gw1  = (const float*)d_in[6];
    const float* gb1  = (const float*)d_in[7];
    const float* rw1  = (const float*)d_in[8];
    const float* rb1  = (const float*)d_in[9];
    const float* bw2  = (const float*)d_in[10];
    const float* bb2  = (const float*)d_in[11];
    const float* gw2  = (const float*)d_in[12];
    const float* gb2  = (const float*)d_in[13];
    const float* rw2  = (const float*)d_in[14];
    const float* rb2  = (const float*)d_in[15];
    const float* bw3  = (const float*)d_in[16];
    const float* bb3  = (const float*)d_in[17];
    const float* gw3  = (const float*)d_in[18];
    const float* gb3  = (const float*)d_in[19];
    const float* fc2w = (const float*)d_in[20];
    const float* fc2b = (const float*)d_in[21];
    float* out = (float*)d_out;
    float* ws  = (float*)d_ws;

    precompute_kernel<<<196, 512, 0, stream>>>(
        packed, fc1w, fc1b,
        bw1, bb1, gw1, gb1, rb1, rw1,
        bw2, bb2, gw2, gb2, rw2, rb2,
        bw3, bb3, gw3, gb3, fc2w, fc2b);

    ldif_main<<<512, 256, 0, stream>>>(samples, ws);

    reduce_kernel<<<32, 256, 0, stream>>>(ws, out);
}